// Round 5
// baseline (325.462 us; speedup 1.0000x reference)
//
#include <hip/hip_runtime.h>
#include <hip/hip_bf16.h>
#include <math.h>

// B=4, T=2048, C=1024, H=16, Dh=64.

typedef __attribute__((ext_vector_type(8))) short short8;   // 8 bf16 (4 VGPRs)
typedef __attribute__((ext_vector_type(4))) float f32x4;

__device__ __forceinline__ short f2bf(float f) {
    __hip_bfloat16 h = __float2bfloat16(f);
    return *reinterpret_cast<short*>(&h);
}
__device__ __forceinline__ float bf2f(short s) {
    __hip_bfloat16 h = *reinterpret_cast<__hip_bfloat16*>(&s);
    return __bfloat162float(h);
}

#define MFMA16(a, b, c) __builtin_amdgcn_mfma_f32_16x16x32_bf16((a), (b), (c), 0, 0, 0)

// async 16B global->LDS (lds dest: wave-uniform base + lane*16)
__device__ __forceinline__ void gload_lds16(const short* g, short* l) {
    __builtin_amdgcn_global_load_lds(
        (const __attribute__((address_space(1))) void*)g,
        (__attribute__((address_space(3))) void*)l, 16, 0, 0);
}

// ---------------------------------------------------------------------------
// Dtype sniff: fp32 inputs (flag=1) vs bf16 (flag=0).
// ---------------------------------------------------------------------------
__global__ void sniff_kernel(const unsigned int* __restrict__ xb,
                             unsigned int* __restrict__ flag)
{
    __shared__ int cnt;
    if (threadIdx.x == 0) cnt = 0;
    __syncthreads();
    int c = 0;
    for (int i = threadIdx.x; i < 4096; i += 256) {
        unsigned e = (xb[i] >> 7) & 0xFFu;
        if (e >= 96u && e <= 142u) ++c;
    }
    atomicAdd(&cnt, c);
    __syncthreads();
    if (threadIdx.x == 0) *flag = (cnt < 2048) ? 1u : 0u;
}

// ---------------------------------------------------------------------------
// x -> bf16 (or straight copy if already bf16).  8192x1024 elems.
// ---------------------------------------------------------------------------
__global__ __launch_bounds__(256)
void cvt_x(const void* __restrict__ in, short* __restrict__ out,
           const unsigned int* __restrict__ flagp)
{
    const bool f32in = (*flagp != 0u);
    const size_t i = ((size_t)blockIdx.x * 256 + threadIdx.x) * 8;
    if (f32in) {
        const float* f = (const float*)in + i;
        f32x4 u0 = *(const f32x4*)f;
        f32x4 u1 = *(const f32x4*)(f + 4);
        short8 v;
#pragma unroll
        for (int j = 0; j < 4; ++j) { v[j] = f2bf(u0[j]); v[j + 4] = f2bf(u1[j]); }
        *(short8*)(out + i) = v;
    } else {
        *(short8*)(out + i) = *(const short8*)((const short*)in + i);
    }
}

// ---------------------------------------------------------------------------
// Transpose + convert-to-bf16: out[c][r] = bf16(in[r][c]).
// ---------------------------------------------------------------------------
__global__ __launch_bounds__(256)
void transpose_cvt(const void* __restrict__ in, short* __restrict__ out,
                   int R, int C, const unsigned int* __restrict__ flagp)
{
    const bool f32in = (*flagp != 0u);
    __shared__ short tile[64][65];
    const int bx = blockIdx.x * 64;
    const int by = blockIdx.y * 64;
    const int tx = threadIdx.x & 63;
    const int ty = threadIdx.x >> 6;
#pragma unroll
    for (int i = 0; i < 64; i += 4) {
        size_t idx = (size_t)(by + ty + i) * C + bx + tx;
        tile[ty + i][tx] = f32in ? f2bf(((const float*)in)[idx])
                                 : ((const short*)in)[idx];
    }
    __syncthreads();
#pragma unroll
    for (int i = 0; i < 64; i += 4)
        out[(size_t)(bx + ty + i) * R + by + tx] = tile[tx][ty + i];
}

// ---------------------------------------------------------------------------
// GEMM: C = A[M][K] (bf16) @ B (Bt[N][K] bf16) + bias.  128x128 tile, BK=32.
// R5: T3-min DOUBLE-BUFFERED staging — STAGE(next->buf^1) issued BEFORE the
// compute of buf[cur]; ONE __syncthreads per K-step (its implicit vmcnt(0)
// drain happens after compute hid the load latency).  Race-free: all reads
// of a buffer complete before the barrier that precedes its next overwrite.
// LDS 32 KB total -> blocks/CU unchanged (4, VGPR-capped).
// EPI=1 (QKV): scatter Q,K [BH][T][64], V transposed [BH][64][T].
//   Q outputs PRE-SCALED by 0.125*log2(e) so attn uses exp2 directly.
// EPI=0 (proj): row-major out, dtype per flag.
// ---------------------------------------------------------------------------
template <int EPI>
__global__ __launch_bounds__(256)
void gemm_kernel(const short* __restrict__ A,
                 const short* __restrict__ Bt,
                 const void* __restrict__ bias,
                 void* __restrict__ O0,
                 short* __restrict__ O1,
                 short* __restrict__ O2,
                 int M, int N, int K,
                 const unsigned int* __restrict__ flagp)
{
    const bool f32io = (*flagp != 0u);
    __shared__ __align__(16) short ldsA[2 * 128 * 32];  // dbuf [m][k] stride 32
    __shared__ __align__(16) short ldsB[2 * 128 * 32];

    const int tid = threadIdx.x;
    const int lane = tid & 63;
    const int wv = tid >> 6;
    const int wm = (wv & 1) * 64;
    const int wn = (wv >> 1) * 64;
    const int tile_m = blockIdx.y * 128;
    const int tile_n = blockIdx.x * 128;

    f32x4 acc[4][4];
#pragma unroll
    for (int i = 0; i < 4; ++i)
#pragma unroll
        for (int j = 0; j < 4; ++j) acc[i][j] = (f32x4){0.f, 0.f, 0.f, 0.f};

    const int ar = lane & 15;
    const int aq = (lane >> 4) * 8;
    const int lrow = lane >> 2;          // 0..15
    const int lcol = (lane & 3) << 3;    // 0,8,16,24

    // stage K-chunk k0 into buffer bsel (4 gload_lds16/thread)
    auto stage = [&](int k0, int bsel) {
#pragma unroll
        for (int p = 0; p < 2; ++p) {
            int c = wv * 2 + p;
            int row = c * 16 + lrow;
            gload_lds16(A + (size_t)(tile_m + row) * K + k0 + lcol,
                        ldsA + bsel * 4096 + c * 512);
            gload_lds16(Bt + (size_t)(tile_n + row) * K + k0 + lcol,
                        ldsB + bsel * 4096 + c * 512);
        }
    };

    stage(0, 0);
    __syncthreads();                       // implicit vmcnt(0): buf0 ready
    int cur = 0;

    for (int k0 = 0; k0 < K; k0 += 32) {
        if (k0 + 32 < K) stage(k0 + 32, cur ^ 1);   // issue-early (overlaps)

        const short* Ab = ldsA + cur * 4096;
        const short* Bb = ldsB + cur * 4096;
        short8 af[4], bfr[4];
#pragma unroll
        for (int i = 0; i < 4; ++i)
            af[i] = *(const short8*)(Ab + (wm + i * 16 + ar) * 32 + aq);
#pragma unroll
        for (int j = 0; j < 4; ++j)
            bfr[j] = *(const short8*)(Bb + (wn + j * 16 + ar) * 32 + aq);
#pragma unroll
        for (int i = 0; i < 4; ++i)
#pragma unroll
            for (int j = 0; j < 4; ++j)
                acc[i][j] = MFMA16(af[i], bfr[j], acc[i][j]);

        __syncthreads();                   // one barrier/step: drains next-stage
        cur ^= 1;
    }

    const int colq = lane & 15;
    const int rowq = (lane >> 4) * 4;
#pragma unroll
    for (int j = 0; j < 4; ++j) {
        int gn = tile_n + wn + j * 16 + colq;
        float bv = f32io ? ((const float*)bias)[gn] : bf2f(((const short*)bias)[gn]);
#pragma unroll
        for (int i = 0; i < 4; ++i) {
#pragma unroll
            for (int r = 0; r < 4; ++r) {
                int gm = tile_m + wm + i * 16 + rowq + r;
                float val = acc[i][j][r] + bv;
                if (EPI == 0) {
                    if (f32io) ((float*)O0)[(size_t)gm * N + gn] = val;
                    else       ((short*)O0)[(size_t)gm * N + gn] = f2bf(val);
                } else {
                    int which = gn >> 10;
                    int c = gn & 1023;
                    int h = c >> 6;
                    int d = c & 63;
                    int b = gm >> 11;
                    int t = gm & 2047;
                    size_t bh = (size_t)(b * 16 + h);
                    // Q pre-scaled: scale * log2(e) = 0.125 * 1.44269504...
                    short o = f2bf(which == 0 ? val * 0.18033688011112042f : val);
                    if (which == 0)      ((short*)O0)[(bh * 2048 + t) * 64 + d] = o;
                    else if (which == 1) O1[(bh * 2048 + t) * 64 + d] = o;
                    else                 O2[(bh * 64 + d) * 2048 + t] = o;  // V^T
                }
            }
        }
    }
}

// ---------------------------------------------------------------------------
// Flash attention, causal, fixed-base softmax (exact: |scores| << 88).
// Q,K: [BH][2048][64], Vt: [BH][64][2048] bf16.  Y: [B][T][C] bf16.
//
// R5: T3-min DOUBLE-BUFFERED K/V tiles (same recipe as GEMM): stage(kt+1)
// issued before compute(kt); ONE barrier per 64-key step (was 2) and the
// stage latency hides under QK+exp+PV.  LDS 42 KB -> 3 blocks/CU (traded
// from 4; stall removal should dominate).  s_setprio(1) around MFMA
// clusters (T5: +4-7% on attn-class structures).
//  - XOR-swizzled tiles (G4/rule 21): linear DMA dest, pre-swizzled global
//    source, same XOR on reads -> conflict-free column-slice ds_read_b128.
//  - Block = tile pair (t, 31-t) -> 33 uniform 64-key steps; 1024 blocks,
//    XCD-chunked (8 bh/XCD -> K/V L2-resident; R1 measured FETCH 650->25MB).
// ---------------------------------------------------------------------------
__global__ __launch_bounds__(256, 4)
void attn_kernel(const short* __restrict__ Q,
                 const short* __restrict__ Kp_,
                 const short* __restrict__ Vt,
                 short* __restrict__ Y)
{
    __shared__ __align__(16) short ldsK[2 * 64 * 64];  // dbuf [key][d], swizzled
    __shared__ __align__(16) short ldsV[2 * 64 * 64];  // dbuf [d][key], swizzled
    __shared__ __align__(16) short pbuf[4][16 * 72];   // per-wave P [16 q][64 k]

    const int tid = threadIdx.x;
    const int lane = tid & 63;
    const int wv = tid >> 6;                  // 0..3
    const int m16 = lane & 15;
    const int quad = lane >> 4;

    // XCD-aware decode: 1024 blocks; xcd = fid&7; 8 bh per XCD;
    // 16 consecutive blocks (tile pairs) per bh.
    const int fid = blockIdx.x;
    const int xcd = fid & 7;
    const int slot = fid >> 3;                // 0..127
    const int bh = (xcd << 3) | (slot >> 4);  // 0..63
    const int g = slot & 15;                  // pair id 0..15

    const int b = bh >> 4, h = bh & 15;

    const short* Qp = Q   + (size_t)bh * 2048 * 64;
    const short* Kp = Kp_ + (size_t)bh * 2048 * 64;
    const short* Vp = Vt  + (size_t)bh * 64 * 2048;
    short* pw = pbuf[wv];

    // per-lane staging constants: 8 rows/wave-call, slot = lane&7 (16B units)
    const int srow = lane >> 3;                           // 0..7 within call
    const int sw = (((lane & 7) ^ (srow & 7)) << 3);      // swizzled col, shorts
    const int swr = ((m16 & 7) << 3);                     // read-side XOR, shorts

    // stage K/V tile at key-offset kb into buffer bsel (4 gload_lds16/thread)
    auto stage = [&](int kb, int bsel) {
#pragma unroll
        for (int p = 0; p < 2; ++p) {
            const int c8 = wv * 2 + p;
            const int row = c8 * 8 + srow;
            gload_lds16(Kp + (size_t)(kb + row) * 64 + sw,
                        ldsK + bsel * 4096 + c8 * 512);
            gload_lds16(Vp + (size_t)row * 2048 + kb + sw,
                        ldsV + bsel * 4096 + c8 * 512);
        }
    };

#pragma unroll
    for (int pass = 0; pass < 2; ++pass) {
        const int t = pass ? (31 - g) : g;        // 64-row tile index 0..31
        const int qbase = t * 64 + wv * 16;       // this wave's 16 q-rows

        stage(0, 0);                              // prologue for this pass

        short8 aq0 = *(const short8*)(Qp + (size_t)(qbase + m16) * 64 + quad * 8);
        short8 aq1 = *(const short8*)(Qp + (size_t)(qbase + m16) * 64 + 32 + quad * 8);

        __syncthreads();                          // implicit vmcnt(0): buf0 ready
        int cur = 0;

        f32x4 o[4];
#pragma unroll
        for (int dt = 0; dt < 4; ++dt) o[dt] = (f32x4){0.f, 0.f, 0.f, 0.f};
        float lrow[4] = {0.f, 0.f, 0.f, 0.f};

        for (int kt = 0; kt <= t; ++kt) {
            const int kb = kt << 6;
            if (kt < t) stage(kb + 64, cur ^ 1);  // issue-early (overlaps)

            const short* kbase = ldsK + cur * 4096;
            const short* vbase = ldsV + cur * 4096;

            // ---- QK^T: 4 key-blocks x 2 k-chunks ----
            f32x4 s[4];
            __builtin_amdgcn_s_setprio(1);
#pragma unroll
            for (int c = 0; c < 4; ++c) {
                const short* kr = kbase + (c * 16 + m16) * 64;
                short8 kf0 = *(const short8*)(kr + ((quad * 8) ^ swr));
                short8 kf1 = *(const short8*)(kr + ((quad * 8 + 32) ^ swr));
                f32x4 z = (f32x4){0.f, 0.f, 0.f, 0.f};
                z = MFMA16(aq0, kf0, z);
                z = MFMA16(aq1, kf1, z);
                s[c] = z;
            }
            __builtin_amdgcn_s_setprio(0);

            // ---- exp + causal mask + P store (fixed-base; Q pre-scaled) ----
#pragma unroll
            for (int c = 0; c < 4; ++c) {
                const int key = kb + c * 16 + m16;
                const bool needmask = (kb + c * 16 + 15 > qbase);
#pragma unroll
                for (int r = 0; r < 4; ++r) {
                    float p = exp2f(s[c][r]);
                    if (needmask && key > qbase + quad * 4 + r) p = 0.f;
                    lrow[r] += p;
                    pw[(quad * 4 + r) * 72 + c * 16 + m16] = f2bf(p);
                }
            }

            // P (C-layout) -> A-operand via per-wave LDS round-trip
            asm volatile("" ::: "memory");
            short8 ap0 = *(const short8*)(pw + m16 * 72 + quad * 8);
            short8 ap1 = *(const short8*)(pw + m16 * 72 + quad * 8 + 32);
            asm volatile("" ::: "memory");

            // ---- PV: 4 d-blocks x 2 k-chunks ----
            __builtin_amdgcn_s_setprio(1);
#pragma unroll
            for (int dt = 0; dt < 4; ++dt) {
                const short* vr = vbase + (dt * 16 + m16) * 64;
                short8 vf0 = *(const short8*)(vr + ((quad * 8) ^ swr));
                short8 vf1 = *(const short8*)(vr + ((quad * 8 + 32) ^ swr));
                o[dt] = MFMA16(ap0, vf0, o[dt]);
                o[dt] = MFMA16(ap1, vf1, o[dt]);
            }
            __builtin_amdgcn_s_setprio(0);

            __syncthreads();              // one barrier/step: drains next-stage
            cur ^= 1;
        }

        // row-sum reduce over the 16 key-lanes (xor within m16 group)
        float linv[4];
#pragma unroll
        for (int r = 0; r < 4; ++r) {
            float sm = lrow[r];
#pragma unroll
            for (int off = 1; off < 16; off <<= 1)
                sm += __shfl_xor(sm, off);
            linv[r] = 1.0f / sm;
        }
#pragma unroll
        for (int dt = 0; dt < 4; ++dt) {
#pragma unroll
            for (int r = 0; r < 4; ++r) {
                int row = qbase + quad * 4 + r;
                int col = h * 64 + dt * 16 + m16;
                Y[((size_t)(b * 2048 + row)) * 1024 + col] = f2bf(o[dt][r] * linv[r]);
            }
        }
        // pass boundary safe: trailing __syncthreads of the kt-loop ran after
        // all LDS reads of the final tile.
    }
}

// ---------------------------------------------------------------------------
extern "C" void kernel_launch(void* const* d_in, const int* in_sizes, int n_in,
                              void* d_out, int out_size, void* d_ws, size_t ws_size,
                              hipStream_t stream)
{
    const void* x      = d_in[0];
    const void* w_attn = d_in[1];
    const void* b_attn = d_in[2];
    const void* w_proj = d_in[3];
    const void* b_proj = d_in[4];

    char* ws = (char*)d_ws;
    unsigned int* flag = (unsigned int*)(ws + 0);
    short* Wta = (short*)(ws + 256);
    short* Wtp = (short*)(ws + 6291712);
    short* Qb  = (short*)(ws + 8388864);
    short* Kb  = (short*)(ws + 25166080);
    short* Vtb = (short*)(ws + 41943296);
    short* Yb  = (short*)(ws + 58720512);
    // Xb (bf16 x) REUSES the Yb slot: Xb's lifetime (cvt_x -> QKV gemm)
    // ends before Yb's begins (attn -> proj gemm); same stream, sequential.
    short* Xb  = (short*)(ws + 58720512);

    sniff_kernel<<<1, 256, 0, stream>>>((const unsigned int*)x, flag);
    cvt_x<<<dim3(4096), 256, 0, stream>>>(x, Xb, flag);
    transpose_cvt<<<dim3(48, 16), 256, 0, stream>>>(w_attn, Wta, 1024, 3072, flag);
    transpose_cvt<<<dim3(16, 16), 256, 0, stream>>>(w_proj, Wtp, 1024, 1024, flag);
    gemm_kernel<1><<<dim3(24, 64), 256, 0, stream>>>(Xb, Wta, b_attn, Qb, Kb, Vtb,
                                                     8192, 3072, 1024, flag);
    attn_kernel<<<dim3(1024), 256, 0, stream>>>(Qb, Kb, Vtb, Yb);
    gemm_kernel<0><<<dim3(8, 64), 256, 0, stream>>>(Yb, Wtp, b_proj, d_out, nullptr, nullptr,
                                                    8192, 1024, 1024, flag);
}

// Round 6
// 324.884 us; speedup vs baseline: 1.0018x; 1.0018x over previous
//
#include <hip/hip_runtime.h>
#include <hip/hip_bf16.h>
#include <math.h>

// B=4, T=2048, C=1024, H=16, Dh=64.

typedef __attribute__((ext_vector_type(8))) short short8;   // 8 bf16 (4 VGPRs)
typedef __attribute__((ext_vector_type(4))) float f32x4;

__device__ __forceinline__ short f2bf(float f) {
    __hip_bfloat16 h = __float2bfloat16(f);
    return *reinterpret_cast<short*>(&h);
}
__device__ __forceinline__ float bf2f(short s) {
    __hip_bfloat16 h = *reinterpret_cast<__hip_bfloat16*>(&s);
    return __bfloat162float(h);
}

#define MFMA16(a, b, c) __builtin_amdgcn_mfma_f32_16x16x32_bf16((a), (b), (c), 0, 0, 0)

// async 16B global->LDS (lds dest: wave-uniform base + lane*16)
__device__ __forceinline__ void gload_lds16(const short* g, short* l) {
    __builtin_amdgcn_global_load_lds(
        (const __attribute__((address_space(1))) void*)g,
        (__attribute__((address_space(3))) void*)l, 16, 0, 0);
}

// ---------------------------------------------------------------------------
// Dtype sniff: fp32 inputs (flag=1) vs bf16 (flag=0).
// ---------------------------------------------------------------------------
__global__ void sniff_kernel(const unsigned int* __restrict__ xb,
                             unsigned int* __restrict__ flag)
{
    __shared__ int cnt;
    if (threadIdx.x == 0) cnt = 0;
    __syncthreads();
    int c = 0;
    for (int i = threadIdx.x; i < 4096; i += 256) {
        unsigned e = (xb[i] >> 7) & 0xFFu;
        if (e >= 96u && e <= 142u) ++c;
    }
    atomicAdd(&cnt, c);
    __syncthreads();
    if (threadIdx.x == 0) *flag = (cnt < 2048) ? 1u : 0u;
}

// ---------------------------------------------------------------------------
// x -> bf16 (or straight copy if already bf16).  8192x1024 elems.
// ---------------------------------------------------------------------------
__global__ __launch_bounds__(256)
void cvt_x(const void* __restrict__ in, short* __restrict__ out,
           const unsigned int* __restrict__ flagp)
{
    const bool f32in = (*flagp != 0u);
    const size_t i = ((size_t)blockIdx.x * 256 + threadIdx.x) * 8;
    if (f32in) {
        const float* f = (const float*)in + i;
        f32x4 u0 = *(const f32x4*)f;
        f32x4 u1 = *(const f32x4*)(f + 4);
        short8 v;
#pragma unroll
        for (int j = 0; j < 4; ++j) { v[j] = f2bf(u0[j]); v[j + 4] = f2bf(u1[j]); }
        *(short8*)(out + i) = v;
    } else {
        *(short8*)(out + i) = *(const short8*)((const short*)in + i);
    }
}

// ---------------------------------------------------------------------------
// Transpose + convert-to-bf16: out[c][r] = bf16(in[r][c]).
// ---------------------------------------------------------------------------
__global__ __launch_bounds__(256)
void transpose_cvt(const void* __restrict__ in, short* __restrict__ out,
                   int R, int C, const unsigned int* __restrict__ flagp)
{
    const bool f32in = (*flagp != 0u);
    __shared__ short tile[64][65];
    const int bx = blockIdx.x * 64;
    const int by = blockIdx.y * 64;
    const int tx = threadIdx.x & 63;
    const int ty = threadIdx.x >> 6;
#pragma unroll
    for (int i = 0; i < 64; i += 4) {
        size_t idx = (size_t)(by + ty + i) * C + bx + tx;
        tile[ty + i][tx] = f32in ? f2bf(((const float*)in)[idx])
                                 : ((const short*)in)[idx];
    }
    __syncthreads();
#pragma unroll
    for (int i = 0; i < 64; i += 4)
        out[(size_t)(bx + ty + i) * R + by + tx] = tile[tx][ty + i];
}

// ---------------------------------------------------------------------------
// GEMM: C = A[M][K] (bf16) @ B (Bt[N][K] bf16) + bias.  128x128 tile, BK=32.
// T3-min DOUBLE-BUFFERED staging (R5, kept): STAGE(next->buf^1) issued
// BEFORE the compute of buf[cur]; ONE __syncthreads per K-step.
// EPI=1 (QKV): scatter Q,K [BH][T][64], V transposed [BH][64][T].
//   Q outputs PRE-SCALED by 0.125*log2(e) so attn uses exp2 directly.
// EPI=0 (proj): row-major out, dtype per flag.
// ---------------------------------------------------------------------------
template <int EPI>
__global__ __launch_bounds__(256)
void gemm_kernel(const short* __restrict__ A,
                 const short* __restrict__ Bt,
                 const void* __restrict__ bias,
                 void* __restrict__ O0,
                 short* __restrict__ O1,
                 short* __restrict__ O2,
                 int M, int N, int K,
                 const unsigned int* __restrict__ flagp)
{
    const bool f32io = (*flagp != 0u);
    __shared__ __align__(16) short ldsA[2 * 128 * 32];  // dbuf [m][k] stride 32
    __shared__ __align__(16) short ldsB[2 * 128 * 32];

    const int tid = threadIdx.x;
    const int lane = tid & 63;
    const int wv = tid >> 6;
    const int wm = (wv & 1) * 64;
    const int wn = (wv >> 1) * 64;
    const int tile_m = blockIdx.y * 128;
    const int tile_n = blockIdx.x * 128;

    f32x4 acc[4][4];
#pragma unroll
    for (int i = 0; i < 4; ++i)
#pragma unroll
        for (int j = 0; j < 4; ++j) acc[i][j] = (f32x4){0.f, 0.f, 0.f, 0.f};

    const int ar = lane & 15;
    const int aq = (lane >> 4) * 8;
    const int lrow = lane >> 2;          // 0..15
    const int lcol = (lane & 3) << 3;    // 0,8,16,24

    // stage K-chunk k0 into buffer bsel (4 gload_lds16/thread)
    auto stage = [&](int k0, int bsel) {
#pragma unroll
        for (int p = 0; p < 2; ++p) {
            int c = wv * 2 + p;
            int row = c * 16 + lrow;
            gload_lds16(A + (size_t)(tile_m + row) * K + k0 + lcol,
                        ldsA + bsel * 4096 + c * 512);
            gload_lds16(Bt + (size_t)(tile_n + row) * K + k0 + lcol,
                        ldsB + bsel * 4096 + c * 512);
        }
    };

    stage(0, 0);
    __syncthreads();                       // implicit vmcnt(0): buf0 ready
    int cur = 0;

    for (int k0 = 0; k0 < K; k0 += 32) {
        if (k0 + 32 < K) stage(k0 + 32, cur ^ 1);   // issue-early (overlaps)

        const short* Ab = ldsA + cur * 4096;
        const short* Bb = ldsB + cur * 4096;
        short8 af[4], bfr[4];
#pragma unroll
        for (int i = 0; i < 4; ++i)
            af[i] = *(const short8*)(Ab + (wm + i * 16 + ar) * 32 + aq);
#pragma unroll
        for (int j = 0; j < 4; ++j)
            bfr[j] = *(const short8*)(Bb + (wn + j * 16 + ar) * 32 + aq);
#pragma unroll
        for (int i = 0; i < 4; ++i)
#pragma unroll
            for (int j = 0; j < 4; ++j)
                acc[i][j] = MFMA16(af[i], bfr[j], acc[i][j]);

        __syncthreads();                   // one barrier/step: drains next-stage
        cur ^= 1;
    }

    const int colq = lane & 15;
    const int rowq = (lane >> 4) * 4;
#pragma unroll
    for (int j = 0; j < 4; ++j) {
        int gn = tile_n + wn + j * 16 + colq;
        float bv = f32io ? ((const float*)bias)[gn] : bf2f(((const short*)bias)[gn]);
#pragma unroll
        for (int i = 0; i < 4; ++i) {
#pragma unroll
            for (int r = 0; r < 4; ++r) {
                int gm = tile_m + wm + i * 16 + rowq + r;
                float val = acc[i][j][r] + bv;
                if (EPI == 0) {
                    if (f32io) ((float*)O0)[(size_t)gm * N + gn] = val;
                    else       ((short*)O0)[(size_t)gm * N + gn] = f2bf(val);
                } else {
                    int which = gn >> 10;
                    int c = gn & 1023;
                    int h = c >> 6;
                    int d = c & 63;
                    int b = gm >> 11;
                    int t = gm & 2047;
                    size_t bh = (size_t)(b * 16 + h);
                    // Q pre-scaled: scale * log2(e) = 0.125 * 1.44269504...
                    short o = f2bf(which == 0 ? val * 0.18033688011112042f : val);
                    if (which == 0)      ((short*)O0)[(bh * 2048 + t) * 64 + d] = o;
                    else if (which == 1) O1[(bh * 2048 + t) * 64 + d] = o;
                    else                 O2[(bh * 64 + d) * 2048 + t] = o;  // V^T
                }
            }
        }
    }
}

// ---------------------------------------------------------------------------
// Flash attention, causal, fixed-base softmax (exact: |scores| << 88).
// Q,K: [BH][2048][64], Vt: [BH][64][2048] bf16.  Y: [B][T][C] bf16.
//
// R6 (fixing R5's silent occupancy loss + dead mask VALU):
//  - LDS shrunk to EXACTLY 40960 B (K/V dbuf 32768 + swizzled pbuf 8192)
//    -> 4 blocks/CU restored (R5's 41984 B fit only 3: 42*4 > 160KB).
//    pbuf stride 72 (+pad) replaced by stride 64 + XOR swizzle
//    (addr = q*64 + (key ^ ((q&7)<<3))): writes stay <=2-way (free),
//    reads of 8 consecutive keys stay contiguous & 16B-aligned because
//    the XOR term only touches bits 3-5 and read bases are multiples of 8.
//  - MASK-SPLIT k-loop: for kt<t, kb+63 < qbase (qbase = t*64+wv*16), so
//    the causal mask is provably dead -> unmasked exp path (saves 16 cmp +
//    16 cndmask per step on 32 of 33 steps; VALU was 57% busy).
//  - Kept from R5: 1-barrier dbuf pipeline (stage(kt+1) before compute(kt)),
//    s_setprio around MFMA clusters, XOR-swizzled K/V tiles, XCD chunking
//    (8 bh/XCD -> K/V L2-resident; FETCH 650MB -> 25MB measured in R1).
// ---------------------------------------------------------------------------
__global__ __launch_bounds__(256, 4)
void attn_kernel(const short* __restrict__ Q,
                 const short* __restrict__ Kp_,
                 const short* __restrict__ Vt,
                 short* __restrict__ Y)
{
    __shared__ __align__(16) short ldsK[2 * 64 * 64];  // dbuf [key][d], swizzled
    __shared__ __align__(16) short ldsV[2 * 64 * 64];  // dbuf [d][key], swizzled
    __shared__ __align__(16) short pbuf[4][16 * 64];   // per-wave P, XOR-swizzled

    const int tid = threadIdx.x;
    const int lane = tid & 63;
    const int wv = tid >> 6;                  // 0..3
    const int m16 = lane & 15;
    const int quad = lane >> 4;

    // XCD-aware decode: 1024 blocks; xcd = fid&7; 8 bh per XCD;
    // 16 consecutive blocks (tile pairs) per bh.
    const int fid = blockIdx.x;
    const int xcd = fid & 7;
    const int slot = fid >> 3;                // 0..127
    const int bh = (xcd << 3) | (slot >> 4);  // 0..63
    const int g = slot & 15;                  // pair id 0..15

    const int b = bh >> 4, h = bh & 15;

    const short* Qp = Q   + (size_t)bh * 2048 * 64;
    const short* Kp = Kp_ + (size_t)bh * 2048 * 64;
    const short* Vp = Vt  + (size_t)bh * 64 * 2048;
    short* pw = pbuf[wv];

    // per-lane staging constants: 8 rows/wave-call, slot = lane&7 (16B units)
    const int srow = lane >> 3;                           // 0..7 within call
    const int sw = (((lane & 7) ^ (srow & 7)) << 3);      // swizzled col, shorts
    const int swr = ((m16 & 7) << 3);                     // K/V read-side XOR
    const int pswr = swr;                                  // pbuf read XOR (q=m16)

    // stage K/V tile at key-offset kb into buffer bsel (4 gload_lds16/thread)
    auto stage = [&](int kb, int bsel) {
#pragma unroll
        for (int p = 0; p < 2; ++p) {
            const int c8 = wv * 2 + p;
            const int row = c8 * 8 + srow;
            gload_lds16(Kp + (size_t)(kb + row) * 64 + sw,
                        ldsK + bsel * 4096 + c8 * 512);
            gload_lds16(Vp + (size_t)row * 2048 + kb + sw,
                        ldsV + bsel * 4096 + c8 * 512);
        }
    };

#pragma unroll
    for (int pass = 0; pass < 2; ++pass) {
        const int t = pass ? (31 - g) : g;        // 64-row tile index 0..31
        const int qbase = t * 64 + wv * 16;       // this wave's 16 q-rows

        stage(0, 0);                              // prologue for this pass

        short8 aq0 = *(const short8*)(Qp + (size_t)(qbase + m16) * 64 + quad * 8);
        short8 aq1 = *(const short8*)(Qp + (size_t)(qbase + m16) * 64 + 32 + quad * 8);

        __syncthreads();                          // implicit vmcnt(0): buf0 ready
        int cur = 0;

        f32x4 o[4];
#pragma unroll
        for (int dt = 0; dt < 4; ++dt) o[dt] = (f32x4){0.f, 0.f, 0.f, 0.f};
        float lrow[4] = {0.f, 0.f, 0.f, 0.f};

        for (int kt = 0; kt <= t; ++kt) {
            const int kb = kt << 6;
            if (kt < t) stage(kb + 64, cur ^ 1);  // issue-early (overlaps)

            const short* kbase = ldsK + cur * 4096;
            const short* vbase = ldsV + cur * 4096;

            // ---- QK^T: 4 key-blocks x 2 k-chunks ----
            f32x4 s[4];
            __builtin_amdgcn_s_setprio(1);
#pragma unroll
            for (int c = 0; c < 4; ++c) {
                const short* kr = kbase + (c * 16 + m16) * 64;
                short8 kf0 = *(const short8*)(kr + ((quad * 8) ^ swr));
                short8 kf1 = *(const short8*)(kr + ((quad * 8 + 32) ^ swr));
                f32x4 z = (f32x4){0.f, 0.f, 0.f, 0.f};
                z = MFMA16(aq0, kf0, z);
                z = MFMA16(aq1, kf1, z);
                s[c] = z;
            }
            __builtin_amdgcn_s_setprio(0);

            // ---- exp + P store (fixed-base; Q pre-scaled).  Mask-split:
            // kt < t  -> causal mask provably dead (kb+63 < qbase).
            // kt == t -> masked path (runs once per pass). ----
            if (kt < t) {
#pragma unroll
                for (int c = 0; c < 4; ++c) {
#pragma unroll
                    for (int r = 0; r < 4; ++r) {
                        const int qrow = quad * 4 + r;
                        float p = exp2f(s[c][r]);
                        lrow[r] += p;
                        pw[qrow * 64 + ((c * 16 + m16) ^ ((qrow & 7) << 3))] = f2bf(p);
                    }
                }
            } else {
#pragma unroll
                for (int c = 0; c < 4; ++c) {
                    const int key = kb + c * 16 + m16;
                    const bool needmask = (kb + c * 16 + 15 > qbase);
#pragma unroll
                    for (int r = 0; r < 4; ++r) {
                        const int qrow = quad * 4 + r;
                        float p = exp2f(s[c][r]);
                        if (needmask && key > qbase + qrow) p = 0.f;
                        lrow[r] += p;
                        pw[qrow * 64 + ((c * 16 + m16) ^ ((qrow & 7) << 3))] = f2bf(p);
                    }
                }
            }

            // P (C-layout) -> A-operand via per-wave LDS round-trip
            asm volatile("" ::: "memory");
            short8 ap0 = *(const short8*)(pw + m16 * 64 + ((quad * 8) ^ pswr));
            short8 ap1 = *(const short8*)(pw + m16 * 64 + ((quad * 8 + 32) ^ pswr));
            asm volatile("" ::: "memory");

            // ---- PV: 4 d-blocks x 2 k-chunks ----
            __builtin_amdgcn_s_setprio(1);
#pragma unroll
            for (int dt = 0; dt < 4; ++dt) {
                const short* vr = vbase + (dt * 16 + m16) * 64;
                short8 vf0 = *(const short8*)(vr + ((quad * 8) ^ swr));
                short8 vf1 = *(const short8*)(vr + ((quad * 8 + 32) ^ swr));
                o[dt] = MFMA16(ap0, vf0, o[dt]);
                o[dt] = MFMA16(ap1, vf1, o[dt]);
            }
            __builtin_amdgcn_s_setprio(0);

            __syncthreads();              // one barrier/step: drains next-stage
            cur ^= 1;
        }

        // row-sum reduce over the 16 key-lanes (xor within m16 group)
        float linv[4];
#pragma unroll
        for (int r = 0; r < 4; ++r) {
            float sm = lrow[r];
#pragma unroll
            for (int off = 1; off < 16; off <<= 1)
                sm += __shfl_xor(sm, off);
            linv[r] = 1.0f / sm;
        }
#pragma unroll
        for (int dt = 0; dt < 4; ++dt) {
#pragma unroll
            for (int r = 0; r < 4; ++r) {
                int row = qbase + quad * 4 + r;
                int col = h * 64 + dt * 16 + m16;
                Y[((size_t)(b * 2048 + row)) * 1024 + col] = f2bf(o[dt][r] * linv[r]);
            }
        }
        // pass boundary safe: trailing __syncthreads of the kt-loop ran after
        // all LDS reads of the final tile.
    }
}

// ---------------------------------------------------------------------------
extern "C" void kernel_launch(void* const* d_in, const int* in_sizes, int n_in,
                              void* d_out, int out_size, void* d_ws, size_t ws_size,
                              hipStream_t stream)
{
    const void* x      = d_in[0];
    const void* w_attn = d_in[1];
    const void* b_attn = d_in[2];
    const void* w_proj = d_in[3];
    const void* b_proj = d_in[4];

    char* ws = (char*)d_ws;
    unsigned int* flag = (unsigned int*)(ws + 0);
    short* Wta = (short*)(ws + 256);
    short* Wtp = (short*)(ws + 6291712);
    short* Qb  = (short*)(ws + 8388864);
    short* Kb  = (short*)(ws + 25166080);
    short* Vtb = (short*)(ws + 41943296);
    short* Yb  = (short*)(ws + 58720512);
    // Xb (bf16 x) REUSES the Yb slot: Xb's lifetime (cvt_x -> QKV gemm)
    // ends before Yb's begins (attn -> proj gemm); same stream, sequential.
    short* Xb  = (short*)(ws + 58720512);

    sniff_kernel<<<1, 256, 0, stream>>>((const unsigned int*)x, flag);
    cvt_x<<<dim3(4096), 256, 0, stream>>>(x, Xb, flag);
    transpose_cvt<<<dim3(48, 16), 256, 0, stream>>>(w_attn, Wta, 1024, 3072, flag);
    transpose_cvt<<<dim3(16, 16), 256, 0, stream>>>(w_proj, Wtp, 1024, 1024, flag);
    gemm_kernel<1><<<dim3(24, 64), 256, 0, stream>>>(Xb, Wta, b_attn, Qb, Kb, Vtb,
                                                     8192, 3072, 1024, flag);
    attn_kernel<<<dim3(1024), 256, 0, stream>>>(Qb, Kb, Vtb, Yb);
    gemm_kernel<0><<<dim3(8, 64), 256, 0, stream>>>(Yb, Wtp, b_proj, d_out, nullptr, nullptr,
                                                    8192, 1024, 1024, flag);
}